// Round 1
// baseline (480.137 us; speedup 1.0000x reference)
//
#include <hip/hip_runtime.h>
#include <hip/hip_bf16.h>
#include <math.h>

// Problem constants (from reference)
#define VDIM 50000   // K (vocab / nodeNum)
#define BDIM 1024    // M (batch)
#define EDIM 256     // N (embedding)
#define LDIM 17      // Huffman path length

// GEMM tiling
constexpr int BM = 128, BN = 128, BK = 32;
constexpr int LDK = 40;                                   // padded LDS k-stride (elements) to break bank alignment
constexpr int KT_TOTAL = (VDIM + BK - 1) / BK;            // 1563 k-tiles (last has 16 valid)
constexpr int SPLITS = 32;                                // split-K factor
constexpr int KT_PER_SPLIT = (KT_TOTAL + SPLITS - 1) / SPLITS;  // 49

typedef short bf16x8 __attribute__((ext_vector_type(8)));  // 8 bf16 (4 VGPRs)
typedef float f32x4  __attribute__((ext_vector_type(4)));

// Split one float4 into packed bf16 hi (2x uint32) and bf16 lo (2x uint32).
// hi = truncate-to-bf16(v); lo = truncate-to-bf16(v - hi).  v - hi is exact in fp32,
// total representation error <= 2^-16 |v|.
__device__ __forceinline__ void split4(const float4 v, uint32_t hi[2], uint32_t lo[2]) {
    const uint32_t ux = __float_as_uint(v.x), uy = __float_as_uint(v.y),
                   uz = __float_as_uint(v.z), uw = __float_as_uint(v.w);
    const uint32_t hx = ux & 0xFFFF0000u, hy = uy & 0xFFFF0000u,
                   hz = uz & 0xFFFF0000u, hw = uw & 0xFFFF0000u;
    const float lx = v.x - __uint_as_float(hx);
    const float ly = v.y - __uint_as_float(hy);
    const float lz = v.z - __uint_as_float(hz);
    const float lw = v.w - __uint_as_float(hw);
    hi[0] = (hx >> 16) | hy;
    hi[1] = (hz >> 16) | hw;
    lo[0] = (__float_as_uint(lx) >> 16) | (__float_as_uint(ly) & 0xFFFF0000u);
    lo[1] = (__float_as_uint(lz) >> 16) | (__float_as_uint(lw) & 0xFFFF0000u);
}

// emb_partial = x @ W^T accumulated via split-K atomics.
// C[m][n] = sum_k A[m][k] * B[n][k], A = x [BDIM x VDIM], B = W [EDIM x VDIM] (both K-major).
// bf16 split-3: A=Ah+Al, B=Bh+Bl; C ~= Ah*Bh + Ah*Bl + Al*Bh.
__global__ __launch_bounds__(256) void gemm_split3(
    const float* __restrict__ X, const float* __restrict__ Wm, float* __restrict__ emb) {
    __shared__ ushort sAhi[BM * LDK];
    __shared__ ushort sAlo[BM * LDK];
    __shared__ ushort sBhi[BN * LDK];
    __shared__ ushort sBlo[BN * LDK];

    const int tid = threadIdx.x;
    const int bn0 = blockIdx.x * BN;          // E offset
    const int bm0 = blockIdx.y * BM;          // B offset
    const int kt0 = blockIdx.z * KT_PER_SPLIT;
    const int kt1 = min(KT_TOTAL, kt0 + KT_PER_SPLIT);

    const int lane = tid & 63;
    const int wv   = tid >> 6;                // wave 0..3
    const int wm0  = (wv >> 1) * 64;          // wave tile origin in block tile
    const int wn0  = (wv & 1) * 64;
    const int lm   = lane & 15;               // A/B fragment row (m or n)
    const int lk   = (lane >> 4) * 8;         // fragment k-offset (8 bf16 per lane)

    f32x4 acc[4][4] = {};                     // 4x4 subtiles of 16x16, fp32

    // staging map: 256 threads cover 128 rows x 8 float4-chunks in 4 passes
    const int sr = tid >> 3;                  // row 0..31 (+32 per pass)
    const int sc = (tid & 7) * 4;             // k-col offset within tile (multiple of 4)

    for (int kt = kt0; kt < kt1; ++kt) {
        const int k0 = kt * BK;
        __syncthreads();                      // previous iter's LDS reads done
#pragma unroll
        for (int p = 0; p < 4; ++p) {
            const int r  = sr + p * 32;
            const int gk = k0 + sc;
            float4 va = make_float4(0.f, 0.f, 0.f, 0.f);
            float4 vb = va;
            if (gk < VDIM) {                  // gk % 4 == 0 and VDIM % 4 == 0 -> all-or-nothing
                va = *reinterpret_cast<const float4*>(X  + (size_t)(bm0 + r) * VDIM + gk);
                vb = *reinterpret_cast<const float4*>(Wm + (size_t)(bn0 + r) * VDIM + gk);
            }
            uint32_t hi[2], lo[2];
            split4(va, hi, lo);
            *reinterpret_cast<uint2*>(&sAhi[r * LDK + sc]) = make_uint2(hi[0], hi[1]);
            *reinterpret_cast<uint2*>(&sAlo[r * LDK + sc]) = make_uint2(lo[0], lo[1]);
            split4(vb, hi, lo);
            *reinterpret_cast<uint2*>(&sBhi[r * LDK + sc]) = make_uint2(hi[0], hi[1]);
            *reinterpret_cast<uint2*>(&sBlo[r * LDK + sc]) = make_uint2(lo[0], lo[1]);
        }
        __syncthreads();

        bf16x8 ah[4], al[4], bh[4], bl[4];
#pragma unroll
        for (int mi = 0; mi < 4; ++mi) {
            const int row = wm0 + mi * 16 + lm;
            ah[mi] = *reinterpret_cast<const bf16x8*>(&sAhi[row * LDK + lk]);
            al[mi] = *reinterpret_cast<const bf16x8*>(&sAlo[row * LDK + lk]);
        }
#pragma unroll
        for (int ni = 0; ni < 4; ++ni) {
            const int row = wn0 + ni * 16 + lm;
            bh[ni] = *reinterpret_cast<const bf16x8*>(&sBhi[row * LDK + lk]);
            bl[ni] = *reinterpret_cast<const bf16x8*>(&sBlo[row * LDK + lk]);
        }
#pragma unroll
        for (int mi = 0; mi < 4; ++mi)
#pragma unroll
            for (int ni = 0; ni < 4; ++ni) {
                acc[mi][ni] = __builtin_amdgcn_mfma_f32_16x16x32_bf16(ah[mi], bh[ni], acc[mi][ni], 0, 0, 0);
                acc[mi][ni] = __builtin_amdgcn_mfma_f32_16x16x32_bf16(ah[mi], bl[ni], acc[mi][ni], 0, 0, 0);
                acc[mi][ni] = __builtin_amdgcn_mfma_f32_16x16x32_bf16(al[mi], bh[ni], acc[mi][ni], 0, 0, 0);
            }
    }

    // epilogue: C/D layout col = lane&15, row = (lane>>4)*4 + reg  [m89/m91-verified]
    const int orow = (lane >> 4) * 4;
#pragma unroll
    for (int mi = 0; mi < 4; ++mi)
#pragma unroll
        for (int ni = 0; ni < 4; ++ni)
#pragma unroll
            for (int r = 0; r < 4; ++r) {
                const int gm = bm0 + wm0 + mi * 16 + orow + r;
                const int gn = bn0 + wn0 + ni * 16 + lm;
                atomicAdd(&emb[gm * EDIM + gn], acc[mi][ni][r]);
            }
}

// Stage 2: per batch row b, out[b] = prod_l sigmoid( sign_l * <pv[b,l,:], emb[b,:]+bias> )
__global__ __launch_bounds__(256) void stage2_kernel(
    const float* __restrict__ emb, const float* __restrict__ bias,
    const float* __restrict__ pv, const int* __restrict__ signs,
    float* __restrict__ out) {
    const int b = blockIdx.x;
    __shared__ float se[EDIM];
    __shared__ float wp[4];
    const int t = threadIdx.x;
    se[t] = emb[b * EDIM + t] + bias[t];
    __syncthreads();
    const int w = t >> 6, lane = t & 63;
    float p = 1.0f;
    for (int l = w; l < LDIM; l += 4) {       // wave 0: l=0,4,8,12,16; waves 1-3: 4 each
        const float4 a = *reinterpret_cast<const float4*>(&pv[((size_t)b * LDIM + l) * EDIM + lane * 4]);
        const float4 e = *reinterpret_cast<const float4*>(&se[lane * 4]);
        float d = a.x * e.x + a.y * e.y + a.z * e.z + a.w * e.w;
#pragma unroll
        for (int off = 32; off > 0; off >>= 1) d += __shfl_xor(d, off, 64);
        const float z = signs[b * LDIM + l] ? d : -d;
        p *= 1.0f / (1.0f + expf(-z));
    }
    if (lane == 0) wp[w] = p;
    __syncthreads();
    if (t == 0) out[b] = wp[0] * wp[1] * wp[2] * wp[3];
}

extern "C" void kernel_launch(void* const* d_in, const int* in_sizes, int n_in,
                              void* d_out, int out_size, void* d_ws, size_t ws_size,
                              hipStream_t stream) {
    const float* X    = (const float*)d_in[0];   // [B, V]
    const float* Wm   = (const float*)d_in[1];   // [E, V]
    const float* bias = (const float*)d_in[2];   // [E]
    const float* pv   = (const float*)d_in[3];   // [B, L, E]
    const int*   sg   = (const int*)d_in[4];     // [B, L]
    float* out = (float*)d_out;                  // [B]
    float* emb = (float*)d_ws;                   // [B, E] fp32 accumulator (1 MB)

    hipMemsetAsync(emb, 0, (size_t)BDIM * EDIM * sizeof(float), stream);

    dim3 grid(EDIM / BN, BDIM / BM, SPLITS);     // 2 x 8 x 32 = 512 blocks
    gemm_split3<<<grid, 256, 0, stream>>>(X, Wm, emb);

    stage2_kernel<<<BDIM, 256, 0, stream>>>(emb, bias, pv, sg, out);
}